// Round 1
// baseline (65.307 us; speedup 1.0000x reference)
//
#include <hip/hip_runtime.h>

#define Bn 4
#define Ln 512
#define Hn 768
#define Sn 100
#define Rn 100
#define En 128
#define TEn 8
#define TRn 6
#define NEGF (-1e20f)

// ---------------------------------------------------------------------------
// K1: masked max over sequence positions for entity spans and relation
// contexts. One block (256 threads) per span. Mask is compacted into an LDS
// position list, then each thread max-reduces its strided H-dims across the
// active positions (coalesced reads of h rows).
// ---------------------------------------------------------------------------
__global__ void __launch_bounds__(256)
masked_max_kernel(const float* __restrict__ hid,
                  const int* __restrict__ ent_mask,
                  const int* __restrict__ rel_mask,
                  const int* __restrict__ sample_mask,
                  float* __restrict__ entity,
                  float* __restrict__ relctx,
                  int* __restrict__ entcnt) {
    int blk = blockIdx.x;                 // 0 .. B*(S+R)-1
    int b = blk / (Sn + Rn);
    int idx = blk % (Sn + Rn);
    bool is_rel = idx >= Sn;
    int span = is_rel ? idx - Sn : idx;

    const int* mask = is_rel ? rel_mask + ((size_t)b * Rn + span) * Ln
                             : ent_mask + ((size_t)b * Sn + span) * Ln;

    __shared__ int pos[Ln];
    __shared__ int cnt_s;
    int tid = threadIdx.x;
    if (tid == 0) cnt_s = 0;
    __syncthreads();
    for (int l = tid; l < Ln; l += 256) {
        if (mask[l] != 0) {
            int p = atomicAdd(&cnt_s, 1);
            pos[p] = l;
        }
    }
    __syncthreads();
    int cnt = cnt_s;

    const float* hb = hid + (size_t)b * Ln * Hn;
    float* out = is_rel ? relctx + ((size_t)b * Rn + span) * Hn
                        : entity + ((size_t)b * Sn + span) * Hn;
    bool zero_out = is_rel && (sample_mask[b * Rn + span] == 1);

    for (int d = tid; d < Hn; d += 256) {
        float m = NEGF;
        for (int i = 0; i < cnt; ++i)
            m = fmaxf(m, hb[(size_t)pos[i] * Hn + d]);
        out[d] = zero_out ? 0.0f : m;
    }
    if (!is_rel && tid == 0) entcnt[b * Sn + span] = cnt;
}

// ---------------------------------------------------------------------------
// Shared reduction helper: 256 threads, per-thread acc[NT] -> out row
// ---------------------------------------------------------------------------
template <int NT>
__device__ __forceinline__ void block_reduce_store(float* acc,
                                                   const float* __restrict__ bias,
                                                   float* __restrict__ out_row,
                                                   int tid) {
    #pragma unroll
    for (int t = 0; t < NT; ++t)
        #pragma unroll
        for (int off = 32; off > 0; off >>= 1)
            acc[t] += __shfl_down(acc[t], off, 64);
    __shared__ float red[4][NT];
    int wave = tid >> 6, lane = tid & 63;
    if (lane == 0) {
        #pragma unroll
        for (int t = 0; t < NT; ++t) red[wave][t] = acc[t];
    }
    __syncthreads();
    if (tid < NT) {
        float s = bias[tid];
        #pragma unroll
        for (int w = 0; w < 4; ++w) s += red[w][tid];
        out_row[tid] = s;
    }
}

// ---------------------------------------------------------------------------
// K2: entity_logit[b,s,:] = [entity | context | size_emb[cnt]] @ span_w + b
// One block per (b,s). K = 2H + E = 1664.
// ---------------------------------------------------------------------------
__global__ void __launch_bounds__(256)
entity_logit_kernel(const float* __restrict__ hid,
                    const float* __restrict__ entity,
                    const int* __restrict__ entcnt,
                    const float* __restrict__ size_emb,
                    const float* __restrict__ span_w,
                    const float* __restrict__ span_b,
                    float* __restrict__ out) {
    int blk = blockIdx.x;                 // b*S + s
    int b = blk / Sn;
    int tid = threadIdx.x;
    const float* ent = entity + (size_t)blk * Hn;
    const float* ctx = hid + (size_t)b * Ln * Hn;           // row l=0
    const float* sz = size_emb + (size_t)entcnt[blk] * En;

    float acc[TEn];
    #pragma unroll
    for (int t = 0; t < TEn; ++t) acc[t] = 0.0f;

    const int K = 2 * Hn + En;            // 1664
    for (int k = tid; k < K; k += 256) {
        float v;
        if (k < Hn)          v = ent[k];
        else if (k < 2 * Hn) v = ctx[k - Hn];
        else                 v = sz[k - 2 * Hn];
        const float* w = span_w + (size_t)k * TEn;
        #pragma unroll
        for (int t = 0; t < TEn; ++t) acc[t] += v * w[t];
    }
    block_reduce_store<TEn>(acc, span_b, out + (size_t)blk * TEn, tid);
}

// ---------------------------------------------------------------------------
// K3: relation_logit[b,r,:] =
//   [rel_ctx | entity[a0] | entity[a1] | size[a0] | size[a1]] @ rel_w + b
// One block per (b,r). K = 3H + 2E = 2560.
// ---------------------------------------------------------------------------
__global__ void __launch_bounds__(256)
relation_logit_kernel(const float* __restrict__ entity,
                      const float* __restrict__ relctx,
                      const int* __restrict__ relations,
                      const int* __restrict__ entcnt,
                      const float* __restrict__ size_emb,
                      const float* __restrict__ rel_w,
                      const float* __restrict__ rel_b,
                      float* __restrict__ out) {
    int blk = blockIdx.x;                 // b*R + r
    int b = blk / Rn;
    int tid = threadIdx.x;
    int a0 = relations[blk * 2 + 0];
    int a1 = relations[blk * 2 + 1];
    const float* ctx = relctx + (size_t)blk * Hn;
    const float* e0 = entity + ((size_t)b * Sn + a0) * Hn;
    const float* e1 = entity + ((size_t)b * Sn + a1) * Hn;
    const float* s0 = size_emb + (size_t)entcnt[b * Sn + a0] * En;
    const float* s1 = size_emb + (size_t)entcnt[b * Sn + a1] * En;

    float acc[TRn];
    #pragma unroll
    for (int t = 0; t < TRn; ++t) acc[t] = 0.0f;

    const int K = 3 * Hn + 2 * En;        // 2560
    for (int k = tid; k < K; k += 256) {
        float v;
        if (k < Hn)               v = ctx[k];
        else if (k < 2 * Hn)      v = e0[k - Hn];
        else if (k < 3 * Hn)      v = e1[k - 2 * Hn];
        else if (k < 3 * Hn + En) v = s0[k - 3 * Hn];
        else                      v = s1[k - 3 * Hn - En];
        const float* w = rel_w + (size_t)k * TRn;
        #pragma unroll
        for (int t = 0; t < TRn; ++t) acc[t] += v * w[t];
    }
    block_reduce_store<TRn>(acc, rel_b, out + (size_t)blk * TRn, tid);
}

extern "C" void kernel_launch(void* const* d_in, const int* in_sizes, int n_in,
                              void* d_out, int out_size, void* d_ws, size_t ws_size,
                              hipStream_t stream) {
    const float* hid        = (const float*)d_in[0];   // (B,L,H)
    const int*   ent_mask   = (const int*)d_in[1];     // (B,S,L)
    const int*   relations  = (const int*)d_in[2];     // (B,R,2)
    const int*   rel_mask   = (const int*)d_in[3];     // (B,R,L)
    const int*   samp_mask  = (const int*)d_in[4];     // (B,R)
    const float* size_emb   = (const float*)d_in[5];   // (100,E)
    const float* span_w     = (const float*)d_in[6];   // (2H+E, TE)
    const float* span_b     = (const float*)d_in[7];   // (TE,)
    const float* rel_w      = (const float*)d_in[8];   // (3H+2E, TR)
    const float* rel_b      = (const float*)d_in[9];   // (TR,)

    float* out = (float*)d_out;
    float* out_ent = out;                       // (B,S,TE) = 3200
    float* out_rel = out + Bn * Sn * TEn;       // (B,R,TR) = 2400

    // workspace layout
    char* ws = (char*)d_ws;
    float* entity = (float*)ws;                               // B*S*H
    float* relctx = entity + (size_t)Bn * Sn * Hn;            // B*R*H
    int*   entcnt = (int*)(relctx + (size_t)Bn * Rn * Hn);    // B*S

    masked_max_kernel<<<Bn * (Sn + Rn), 256, 0, stream>>>(
        hid, ent_mask, rel_mask, samp_mask, entity, relctx, entcnt);

    entity_logit_kernel<<<Bn * Sn, 256, 0, stream>>>(
        hid, entity, entcnt, size_emb, span_w, span_b, out_ent);

    relation_logit_kernel<<<Bn * Rn, 256, 0, stream>>>(
        entity, relctx, relations, entcnt, size_emb, rel_w, rel_b, out_rel);
}

// Round 2
// 24.259 us; speedup vs baseline: 2.6921x; 2.6921x over previous
//
#include <hip/hip_runtime.h>

#define Bn 4
#define Ln 512
#define Hn 768
#define Sn 100
#define Rn 100
#define En 128
#define TEn 8
#define TRn 6
#define NEGF (-1e20f)
#define CHUNKS 3            // Hn / 256 dims per chunk

// ---------------------------------------------------------------------------
// K1: masked max. Grid = B*(S+R)*CHUNKS blocks; each block handles 256 dims
// (1 dim/thread) of one span. Mask compacted to LDS pos list (order
// irrelevant for max). Row loop unrolled x4 for 4 loads in flight.
// ---------------------------------------------------------------------------
__global__ void __launch_bounds__(256)
masked_max_kernel(const float* __restrict__ hid,
                  const int* __restrict__ ent_mask,
                  const int* __restrict__ rel_mask,
                  const int* __restrict__ sample_mask,
                  float* __restrict__ entity,
                  float* __restrict__ relctx,
                  int* __restrict__ entcnt) {
    int blk = blockIdx.x;
    int span_id = blk / CHUNKS;           // 0 .. B*(S+R)-1
    int chunk = blk % CHUNKS;
    int b = span_id / (Sn + Rn);
    int idx = span_id % (Sn + Rn);
    bool is_rel = idx >= Sn;
    int span = is_rel ? idx - Sn : idx;

    const int* mask = is_rel ? rel_mask + ((size_t)b * Rn + span) * Ln
                             : ent_mask + ((size_t)b * Sn + span) * Ln;

    __shared__ int pos[Ln];
    __shared__ int cnt_s;
    int tid = threadIdx.x;
    if (tid == 0) cnt_s = 0;
    __syncthreads();
    #pragma unroll
    for (int l = tid; l < Ln; l += 256) {
        if (mask[l] != 0) {
            int p = atomicAdd(&cnt_s, 1);
            pos[p] = l;
        }
    }
    __syncthreads();
    int cnt = cnt_s;

    int d = chunk * 256 + tid;
    const float* hp = hid + (size_t)b * Ln * Hn + d;
    float* out = is_rel ? relctx + ((size_t)b * Rn + span) * Hn
                        : entity + ((size_t)b * Sn + span) * Hn;
    bool zero_out = is_rel && (sample_mask[b * Rn + span] == 1);

    float m = NEGF;
    int i = 0;
    for (; i + 4 <= cnt; i += 4) {
        float v0 = hp[(size_t)pos[i + 0] * Hn];
        float v1 = hp[(size_t)pos[i + 1] * Hn];
        float v2 = hp[(size_t)pos[i + 2] * Hn];
        float v3 = hp[(size_t)pos[i + 3] * Hn];
        m = fmaxf(m, fmaxf(fmaxf(v0, v1), fmaxf(v2, v3)));
    }
    for (; i < cnt; ++i)
        m = fmaxf(m, hp[(size_t)pos[i] * Hn]);

    out[d] = zero_out ? 0.0f : m;
    if (chunk == 0 && !is_rel && tid == 0) entcnt[b * Sn + span] = cnt;
}

// ---------------------------------------------------------------------------
// Block reduction helper: 256 threads, per-thread acc[NT] -> out row
// ---------------------------------------------------------------------------
template <int NT>
__device__ __forceinline__ void block_reduce_store(float* acc,
                                                   const float* __restrict__ bias,
                                                   float* __restrict__ out_row,
                                                   int tid) {
    #pragma unroll
    for (int t = 0; t < NT; ++t)
        #pragma unroll
        for (int off = 32; off > 0; off >>= 1)
            acc[t] += __shfl_down(acc[t], off, 64);
    __shared__ float red[4][NT];
    int wave = tid >> 6, lane = tid & 63;
    if (lane == 0) {
        #pragma unroll
        for (int t = 0; t < NT; ++t) red[wave][t] = acc[t];
    }
    __syncthreads();
    if (tid < NT) {
        float s = bias[tid];
        #pragma unroll
        for (int w = 0; w < 4; ++w) s += red[w][tid];
        out_row[tid] = s;
    }
}

// ---------------------------------------------------------------------------
// K2: merged logits. Blocks [0, B*S) -> entity logits; [B*S, B*S+B*R) ->
// relation logits. One block per output row, thread-strided K loop.
// ---------------------------------------------------------------------------
__global__ void __launch_bounds__(256)
logits_kernel(const float* __restrict__ hid,
              const float* __restrict__ entity,
              const float* __restrict__ relctx,
              const int* __restrict__ relations,
              const int* __restrict__ entcnt,
              const float* __restrict__ size_emb,
              const float* __restrict__ span_w,
              const float* __restrict__ span_b,
              const float* __restrict__ rel_w,
              const float* __restrict__ rel_b,
              float* __restrict__ out_ent,
              float* __restrict__ out_rel) {
    int blk = blockIdx.x;
    int tid = threadIdx.x;

    if (blk < Bn * Sn) {
        // ---- entity logit: [entity | ctx | size] @ span_w + b, K = 1664
        int b = blk / Sn;
        const float* ent = entity + (size_t)blk * Hn;
        const float* ctx = hid + (size_t)b * Ln * Hn;     // row l=0
        const float* sz = size_emb + (size_t)entcnt[blk] * En;

        float acc[TEn];
        #pragma unroll
        for (int t = 0; t < TEn; ++t) acc[t] = 0.0f;

        const int K = 2 * Hn + En;
        for (int k = tid; k < K; k += 256) {
            float v;
            if (k < Hn)          v = ent[k];
            else if (k < 2 * Hn) v = ctx[k - Hn];
            else                 v = sz[k - 2 * Hn];
            const float* w = span_w + (size_t)k * TEn;
            #pragma unroll
            for (int t = 0; t < TEn; ++t) acc[t] += v * w[t];
        }
        block_reduce_store<TEn>(acc, span_b, out_ent + (size_t)blk * TEn, tid);
    } else {
        // ---- relation logit: [rel_ctx | e0 | e1 | s0 | s1] @ rel_w, K = 2560
        int rblk = blk - Bn * Sn;                         // b*R + r
        int b = rblk / Rn;
        int a0 = relations[rblk * 2 + 0];
        int a1 = relations[rblk * 2 + 1];
        const float* ctx = relctx + (size_t)rblk * Hn;
        const float* e0 = entity + ((size_t)b * Sn + a0) * Hn;
        const float* e1 = entity + ((size_t)b * Sn + a1) * Hn;
        const float* s0 = size_emb + (size_t)entcnt[b * Sn + a0] * En;
        const float* s1 = size_emb + (size_t)entcnt[b * Sn + a1] * En;

        float acc[TRn];
        #pragma unroll
        for (int t = 0; t < TRn; ++t) acc[t] = 0.0f;

        const int K = 3 * Hn + 2 * En;
        for (int k = tid; k < K; k += 256) {
            float v;
            if (k < Hn)               v = ctx[k];
            else if (k < 2 * Hn)      v = e0[k - Hn];
            else if (k < 3 * Hn)      v = e1[k - 2 * Hn];
            else if (k < 3 * Hn + En) v = s0[k - 3 * Hn];
            else                      v = s1[k - 3 * Hn - En];
            const float* w = rel_w + (size_t)k * TRn;
            #pragma unroll
            for (int t = 0; t < TRn; ++t) acc[t] += v * w[t];
        }
        block_reduce_store<TRn>(acc, rel_b, out_rel + (size_t)rblk * TRn, tid);
    }
}

extern "C" void kernel_launch(void* const* d_in, const int* in_sizes, int n_in,
                              void* d_out, int out_size, void* d_ws, size_t ws_size,
                              hipStream_t stream) {
    const float* hid        = (const float*)d_in[0];   // (B,L,H)
    const int*   ent_mask   = (const int*)d_in[1];     // (B,S,L)
    const int*   relations  = (const int*)d_in[2];     // (B,R,2)
    const int*   rel_mask   = (const int*)d_in[3];     // (B,R,L)
    const int*   samp_mask  = (const int*)d_in[4];     // (B,R)
    const float* size_emb   = (const float*)d_in[5];   // (100,E)
    const float* span_w     = (const float*)d_in[6];   // (2H+E, TE)
    const float* span_b     = (const float*)d_in[7];   // (TE,)
    const float* rel_w      = (const float*)d_in[8];   // (3H+2E, TR)
    const float* rel_b      = (const float*)d_in[9];   // (TR,)

    float* out = (float*)d_out;
    float* out_ent = out;                       // (B,S,TE)
    float* out_rel = out + Bn * Sn * TEn;       // (B,R,TR)

    char* ws = (char*)d_ws;
    float* entity = (float*)ws;                               // B*S*H
    float* relctx = entity + (size_t)Bn * Sn * Hn;            // B*R*H
    int*   entcnt = (int*)(relctx + (size_t)Bn * Rn * Hn);    // B*S

    masked_max_kernel<<<Bn * (Sn + Rn) * CHUNKS, 256, 0, stream>>>(
        hid, ent_mask, rel_mask, samp_mask, entity, relctx, entcnt);

    logits_kernel<<<Bn * Sn + Bn * Rn, 256, 0, stream>>>(
        hid, entity, relctx, relations, entcnt, size_emb,
        span_w, span_b, rel_w, rel_b, out_ent, out_rel);
}

// Round 3
// 23.712 us; speedup vs baseline: 2.7542x; 1.0231x over previous
//
#include <hip/hip_runtime.h>

#define Bn 4
#define Ln 512
#define Hn 768
#define Sn 100
#define Rn 100
#define En 128
#define TEn 8
#define TRn 6
#define NEGF (-1e20f)
#define W 8
#define NBLK (Ln / W)      // 64
#define H4 (Hn / 4)        // 192 float4 per row

__device__ __forceinline__ float4 fmax4(float4 a, float4 b) {
    return make_float4(fmaxf(a.x, b.x), fmaxf(a.y, b.y),
                       fmaxf(a.z, b.z), fmaxf(a.w, b.w));
}

// ---------------------------------------------------------------------------
// P: bmax[b][j][d] = max over rows 8j..8j+7 of hid[b]. One block per (b,j),
// 192 threads, float4 per thread. Reads hid once (6.3 MB), writes 0.8 MB.
// ---------------------------------------------------------------------------
__global__ void __launch_bounds__(192)
blockmax_kernel(const float* __restrict__ hid, float* __restrict__ bmax) {
    int bj = blockIdx.x;                   // b*NBLK + j
    int b = bj / NBLK, j = bj % NBLK;
    int tid = threadIdx.x;
    const float4* src = (const float4*)(hid + ((size_t)b * Ln + j * W) * Hn);
    float4 m = src[tid];
    #pragma unroll
    for (int r = 1; r < W; ++r)
        m = fmax4(m, src[(size_t)r * H4 + tid]);
    ((float4*)(bmax + (size_t)bj * Hn))[tid] = m;
}

// ---------------------------------------------------------------------------
// K1: masked max per span. One 192-thread block per span (float4/thread
// covers all 768 dims). Mask decomposed into full 8-blocks (use bmax) +
// partial-block edge rows (use hid). Count reduced in wave 0.
// ---------------------------------------------------------------------------
__global__ void __launch_bounds__(192)
masked_max_kernel(const float* __restrict__ hid,
                  const int* __restrict__ ent_mask,
                  const int* __restrict__ rel_mask,
                  const int* __restrict__ sample_mask,
                  const float* __restrict__ bmax,
                  float* __restrict__ entity,
                  float* __restrict__ relctx,
                  int* __restrict__ entcnt) {
    int span_id = blockIdx.x;              // 0 .. B*(S+R)-1
    int b = span_id / (Sn + Rn);
    int idx = span_id % (Sn + Rn);
    bool is_rel = idx >= Sn;
    int span = is_rel ? idx - Sn : idx;
    int tid = threadIdx.x;

    float4* out4 = (float4*)(is_rel ? relctx + ((size_t)b * Rn + span) * Hn
                                    : entity + ((size_t)b * Sn + span) * Hn);

    // masked-out relation spans: write zeros, done (no analysis needed)
    if (is_rel && sample_mask[b * Rn + span] == 1) {
        out4[tid] = make_float4(0.f, 0.f, 0.f, 0.f);
        return;
    }

    const int* mask = is_rel ? rel_mask + ((size_t)b * Rn + span) * Ln
                             : ent_mask + ((size_t)b * Sn + span) * Ln;

    __shared__ int rows[Ln];
    __shared__ int blks[NBLK];
    __shared__ int nrows_s, nblks_s, cnt_s;
    if (tid == 0) { nrows_s = 0; nblks_s = 0; }
    __syncthreads();

    int local = 0;
    if (tid < NBLK) {                      // tid 0..63 == wave 0
        const int4* m4 = (const int4*)(mask + tid * W);
        int4 a = m4[0], c = m4[1];
        int mm[8] = {a.x, a.y, a.z, a.w, c.x, c.y, c.z, c.w};
        int s = 0;
        #pragma unroll
        for (int r = 0; r < 8; ++r) s += (mm[r] != 0);
        local = s;
        if (s == 8) {
            int p = atomicAdd(&nblks_s, 1);
            blks[p] = tid;
        } else if (s > 0) {
            #pragma unroll
            for (int r = 0; r < 8; ++r)
                if (mm[r] != 0) { int p = atomicAdd(&nrows_s, 1); rows[p] = tid * W + r; }
        }
        // wave-0 reduction for the set-bit count
        #pragma unroll
        for (int off = 32; off > 0; off >>= 1) local += __shfl_down(local, off, 64);
        if (tid == 0) cnt_s = local;
    }
    __syncthreads();
    int nrows = nrows_s, nblks = nblks_s, cnt = cnt_s;

    const float4* hb4 = (const float4*)(hid + (size_t)b * Ln * Hn);
    const float4* bm4 = (const float4*)(bmax + (size_t)b * NBLK * Hn);

    float4 m = make_float4(NEGF, NEGF, NEGF, NEGF);
    int i = 0;
    for (; i + 2 <= nblks; i += 2) {
        float4 v0 = bm4[(size_t)blks[i] * H4 + tid];
        float4 v1 = bm4[(size_t)blks[i + 1] * H4 + tid];
        m = fmax4(m, fmax4(v0, v1));
    }
    for (; i < nblks; ++i)
        m = fmax4(m, bm4[(size_t)blks[i] * H4 + tid]);
    i = 0;
    for (; i + 2 <= nrows; i += 2) {
        float4 v0 = hb4[(size_t)rows[i] * H4 + tid];
        float4 v1 = hb4[(size_t)rows[i + 1] * H4 + tid];
        m = fmax4(m, fmax4(v0, v1));
    }
    for (; i < nrows; ++i)
        m = fmax4(m, hb4[(size_t)rows[i] * H4 + tid]);

    out4[tid] = m;
    if (!is_rel && tid == 0) entcnt[b * Sn + span] = cnt;
}

// ---------------------------------------------------------------------------
// Block reduction helper: 256 threads, per-thread acc[NT] -> out row
// ---------------------------------------------------------------------------
template <int NT>
__device__ __forceinline__ void block_reduce_store(float* acc,
                                                   const float* __restrict__ bias,
                                                   float* __restrict__ out_row,
                                                   int tid) {
    #pragma unroll
    for (int t = 0; t < NT; ++t)
        #pragma unroll
        for (int off = 32; off > 0; off >>= 1)
            acc[t] += __shfl_down(acc[t], off, 64);
    __shared__ float red[4][NT];
    int wave = tid >> 6, lane = tid & 63;
    if (lane == 0) {
        #pragma unroll
        for (int t = 0; t < NT; ++t) red[wave][t] = acc[t];
    }
    __syncthreads();
    if (tid < NT) {
        float s = bias[tid];
        #pragma unroll
        for (int w = 0; w < 4; ++w) s += red[w][tid];
        out_row[tid] = s;
    }
}

// ---------------------------------------------------------------------------
// K2: merged logits, float4 activations + vector weight loads.
// Blocks [0, B*S): entity logits (K=1664); [B*S, B*S+B*R): relation (K=2560).
// ---------------------------------------------------------------------------
__global__ void __launch_bounds__(256)
logits_kernel(const float* __restrict__ hid,
              const float* __restrict__ entity,
              const float* __restrict__ relctx,
              const int* __restrict__ relations,
              const int* __restrict__ entcnt,
              const float* __restrict__ size_emb,
              const float* __restrict__ span_w,
              const float* __restrict__ span_b,
              const float* __restrict__ rel_w,
              const float* __restrict__ rel_b,
              float* __restrict__ out_ent,
              float* __restrict__ out_rel) {
    int blk = blockIdx.x;
    int tid = threadIdx.x;

    if (blk < Bn * Sn) {
        // ---- entity: [entity | ctx | size] @ span_w + b
        int b = blk / Sn;
        const float4* ent4 = (const float4*)(entity + (size_t)blk * Hn);
        const float4* ctx4 = (const float4*)(hid + (size_t)b * Ln * Hn); // row 0
        const float4* sz4  = (const float4*)(size_emb + (size_t)entcnt[blk] * En);

        float acc[TEn];
        #pragma unroll
        for (int t = 0; t < TEn; ++t) acc[t] = 0.0f;

        const int K4 = (2 * Hn + En) / 4;          // 416
        for (int k4 = tid; k4 < K4; k4 += 256) {
            float4 v;
            if (k4 < H4)          v = ent4[k4];
            else if (k4 < 2 * H4) v = ctx4[k4 - H4];
            else                  v = sz4[k4 - 2 * H4];
            int k = k4 * 4;
            const float4* w4 = (const float4*)(span_w + (size_t)k * TEn);
            const float* vv = &v.x;
            #pragma unroll
            for (int j = 0; j < 4; ++j) {
                float4 wa = w4[j * 2], wb = w4[j * 2 + 1];
                acc[0] += vv[j] * wa.x; acc[1] += vv[j] * wa.y;
                acc[2] += vv[j] * wa.z; acc[3] += vv[j] * wa.w;
                acc[4] += vv[j] * wb.x; acc[5] += vv[j] * wb.y;
                acc[6] += vv[j] * wb.z; acc[7] += vv[j] * wb.w;
            }
        }
        block_reduce_store<TEn>(acc, span_b, out_ent + (size_t)blk * TEn, tid);
    } else {
        // ---- relation: [rel_ctx | e0 | e1 | s0 | s1] @ rel_w + b
        int rblk = blk - Bn * Sn;
        int b = rblk / Rn;
        int a0 = relations[rblk * 2 + 0];
        int a1 = relations[rblk * 2 + 1];
        const float4* ctx4 = (const float4*)(relctx + (size_t)rblk * Hn);
        const float4* e04  = (const float4*)(entity + ((size_t)b * Sn + a0) * Hn);
        const float4* e14  = (const float4*)(entity + ((size_t)b * Sn + a1) * Hn);
        const float4* s04  = (const float4*)(size_emb + (size_t)entcnt[b * Sn + a0] * En);
        const float4* s14  = (const float4*)(size_emb + (size_t)entcnt[b * Sn + a1] * En);

        float acc[TRn];
        #pragma unroll
        for (int t = 0; t < TRn; ++t) acc[t] = 0.0f;

        const int E4 = En / 4;                      // 32
        const int K4 = (3 * Hn + 2 * En) / 4;       // 640
        for (int k4 = tid; k4 < K4; k4 += 256) {
            float4 v;
            if (k4 < H4)               v = ctx4[k4];
            else if (k4 < 2 * H4)      v = e04[k4 - H4];
            else if (k4 < 3 * H4)      v = e14[k4 - 2 * H4];
            else if (k4 < 3 * H4 + E4) v = s04[k4 - 3 * H4];
            else                       v = s14[k4 - 3 * H4 - E4];
            int k = k4 * 4;
            const float* vv = &v.x;
            #pragma unroll
            for (int j = 0; j < 4; ++j) {
                const float2* wr = (const float2*)(rel_w + (size_t)(k + j) * TRn);
                float2 w0 = wr[0], w1 = wr[1], w2 = wr[2];
                acc[0] += vv[j] * w0.x; acc[1] += vv[j] * w0.y;
                acc[2] += vv[j] * w1.x; acc[3] += vv[j] * w1.y;
                acc[4] += vv[j] * w2.x; acc[5] += vv[j] * w2.y;
            }
        }
        block_reduce_store<TRn>(acc, rel_b, out_rel + (size_t)rblk * TRn, tid);
    }
}

extern "C" void kernel_launch(void* const* d_in, const int* in_sizes, int n_in,
                              void* d_out, int out_size, void* d_ws, size_t ws_size,
                              hipStream_t stream) {
    const float* hid        = (const float*)d_in[0];   // (B,L,H)
    const int*   ent_mask   = (const int*)d_in[1];     // (B,S,L)
    const int*   relations  = (const int*)d_in[2];     // (B,R,2)
    const int*   rel_mask   = (const int*)d_in[3];     // (B,R,L)
    const int*   samp_mask  = (const int*)d_in[4];     // (B,R)
    const float* size_emb   = (const float*)d_in[5];   // (100,E)
    const float* span_w     = (const float*)d_in[6];   // (2H+E, TE)
    const float* span_b     = (const float*)d_in[7];   // (TE,)
    const float* rel_w      = (const float*)d_in[8];   // (3H+2E, TR)
    const float* rel_b      = (const float*)d_in[9];   // (TR,)

    float* out = (float*)d_out;
    float* out_ent = out;                       // (B,S,TE)
    float* out_rel = out + Bn * Sn * TEn;       // (B,R,TR)

    char* ws = (char*)d_ws;
    float* entity = (float*)ws;                               // B*S*H
    float* relctx = entity + (size_t)Bn * Sn * Hn;            // B*R*H
    float* bmax   = relctx + (size_t)Bn * Rn * Hn;            // B*NBLK*H
    int*   entcnt = (int*)(bmax + (size_t)Bn * NBLK * Hn);    // B*S

    blockmax_kernel<<<Bn * NBLK, 192, 0, stream>>>(hid, bmax);

    masked_max_kernel<<<Bn * (Sn + Rn), 192, 0, stream>>>(
        hid, ent_mask, rel_mask, samp_mask, bmax, entity, relctx, entcnt);

    logits_kernel<<<Bn * Sn + Bn * Rn, 256, 0, stream>>>(
        hid, entity, relctx, relations, entcnt, size_emb,
        span_w, span_b, rel_w, rel_b, out_ent, out_rel);
}